// Round 2
// baseline (7837.852 us; speedup 1.0000x reference)
//
#include <hip/hip_runtime.h>
#include <math.h>

// Problem constants (fixed by reference)
#define B_N   2
#define S_N   20197
#define M_N   (B_N * S_N)   // 40394 rows
#define D_N   256
#define NH_N  8
#define HD_N  32
#define DFF_N 1024
#define CHUNK_ROWS 10048    // FFN row-chunk so hidden buf fits in value region

// ---------------------------------------------------------------------------
// Reference points: ref[b,s,l,{x,y}]  (B,S,NL,2)
// ---------------------------------------------------------------------------
__global__ void compute_ref_kernel(const float* __restrict__ vr, float* __restrict__ refpts)
{
    int q = blockIdx.x * blockDim.x + threadIdx.x;
    if (q >= M_N) return;
    int b = q / S_N;
    int s = q - b * S_N;
    const int Hs[4] = {100, 50, 25, 13};
    const int Ws[4] = {152, 76, 38, 19};
    int l0, i, j;
    if (s < 15200)      { l0 = 0; i = s / 152; j = s - i * 152; }
    else if (s < 19000) { int t = s - 15200; l0 = 1; i = t / 76; j = t - i * 76; }
    else if (s < 19950) { int t = s - 19000; l0 = 2; i = t / 38; j = t - i * 38; }
    else                { int t = s - 19950; l0 = 3; i = t / 19; j = t - i * 19; }
    float ry = (i + 0.5f) / (vr[(b * 4 + l0) * 2 + 1] * (float)Hs[l0]);
    float rx = (j + 0.5f) / (vr[(b * 4 + l0) * 2 + 0] * (float)Ws[l0]);
#pragma unroll
    for (int l = 0; l < 4; ++l) {
        refpts[(size_t)q * 8 + l * 2 + 0] = rx * vr[(b * 4 + l) * 2 + 0];
        refpts[(size_t)q * 8 + l * 2 + 1] = ry * vr[(b * 4 + l) * 2 + 1];
    }
}

// ---------------------------------------------------------------------------
// fp32 tiled GEMM: C[M,N] = (A (+A2)) @ W[K,N] + bias, optional relu.
// 64x64 tile, BK=16, 256 threads, 4x4 micro-tile per thread.
// ---------------------------------------------------------------------------
__global__ __launch_bounds__(256) void gemm_f32(
    const float* __restrict__ A, const float* __restrict__ A2,
    const float* __restrict__ W, const float* __restrict__ bias,
    float* __restrict__ C, int M, int N, int K, int dorelu)
{
    __shared__ float As[16][68];   // [k][m], padded
    __shared__ float Bs[16][64];   // [k][n]
    const int tid = threadIdx.x;
    const int m0 = blockIdx.x * 64;
    const int n0 = blockIdx.y * 64;
    const int tm = tid >> 4, tn = tid & 15;
    const int am = tid >> 2;            // 0..63 (row within tile)
    const int ak = (tid & 3) * 4;       // 0,4,8,12 (k offset)
    const int bn = tid & 63;
    const int bk0 = tid >> 6;           // 0..3

    float acc[4][4];
#pragma unroll
    for (int i = 0; i < 4; ++i)
#pragma unroll
        for (int j = 0; j < 4; ++j) acc[i][j] = 0.f;

    const int arow = m0 + am;
    for (int k0 = 0; k0 < K; k0 += 16) {
        float4 av = make_float4(0.f, 0.f, 0.f, 0.f);
        if (arow < M) {
            av = *(const float4*)(A + (size_t)arow * K + k0 + ak);
            if (A2) {
                float4 p = *(const float4*)(A2 + (size_t)arow * K + k0 + ak);
                av.x += p.x; av.y += p.y; av.z += p.z; av.w += p.w;
            }
        }
        As[ak + 0][am] = av.x; As[ak + 1][am] = av.y;
        As[ak + 2][am] = av.z; As[ak + 3][am] = av.w;
#pragma unroll
        for (int r = 0; r < 4; ++r) {
            int k = bk0 + r * 4;
            Bs[k][bn] = W[(size_t)(k0 + k) * N + n0 + bn];
        }
        __syncthreads();
#pragma unroll
        for (int kk = 0; kk < 16; ++kk) {
            float4 a4 = *(const float4*)&As[kk][tm * 4];
            float4 b4 = *(const float4*)&Bs[kk][tn * 4];
            float ar[4] = {a4.x, a4.y, a4.z, a4.w};
            float br[4] = {b4.x, b4.y, b4.z, b4.w};
#pragma unroll
            for (int i = 0; i < 4; ++i)
#pragma unroll
                for (int j = 0; j < 4; ++j)
                    acc[i][j] = fmaf(ar[i], br[j], acc[i][j]);
        }
        __syncthreads();
    }
    float4 bb = *(const float4*)(bias + n0 + tn * 4);
#pragma unroll
    for (int i = 0; i < 4; ++i) {
        int row = m0 + tm * 4 + i;
        if (row < M) {
            float4 o;
            o.x = acc[i][0] + bb.x; o.y = acc[i][1] + bb.y;
            o.z = acc[i][2] + bb.z; o.w = acc[i][3] + bb.w;
            if (dorelu) {
                o.x = fmaxf(o.x, 0.f); o.y = fmaxf(o.y, 0.f);
                o.z = fmaxf(o.z, 0.f); o.w = fmaxf(o.w, 0.f);
            }
            *(float4*)(C + (size_t)row * N + n0 + tn * 4) = o;
        }
    }
}

// ---------------------------------------------------------------------------
// MSDA sampling: one block per query. Threads = 8 heads x 32 channels.
// ---------------------------------------------------------------------------
__global__ __launch_bounds__(256) void msda_sample_kernel(
    const float* __restrict__ value,   // (B,S,NH,HD)
    const float* __restrict__ offb,    // (B,S,256) = (h,l,p,2)
    const float* __restrict__ alog,    // (B,S,128) = (h, l*4+p) raw logits
    const float* __restrict__ refpts,  // (B,S,NL,2)
    float* __restrict__ acc)           // (B,S,256) = (h,d)
{
    const int q = blockIdx.x;
    const int b = q / S_N;
    const int tid = threadIdx.x;
    __shared__ float lx[128], ly[128], lw[128];
    const float Wf[4] = {152.f, 76.f, 38.f, 19.f};
    const float Hf[4] = {100.f, 50.f, 25.f, 13.f};
    if (tid < 128) {
        int l = (tid >> 2) & 3;
        float ox = offb[(size_t)q * 256 + tid * 2 + 0];
        float oy = offb[(size_t)q * 256 + tid * 2 + 1];
        lx[tid] = refpts[(size_t)q * 8 + l * 2 + 0] + ox / Wf[l];
        ly[tid] = refpts[(size_t)q * 8 + l * 2 + 1] + oy / Hf[l];
        lw[tid] = alog[(size_t)q * 128 + tid];
    }
    __syncthreads();
    if (tid < 8) {   // per-head softmax over 16 (serial; trivial cost)
        float mx = -1e30f;
        for (int i = 0; i < 16; ++i) mx = fmaxf(mx, lw[tid * 16 + i]);
        float sum = 0.f;
        for (int i = 0; i < 16; ++i) {
            float e = expf(lw[tid * 16 + i] - mx);
            lw[tid * 16 + i] = e; sum += e;
        }
        float inv = 1.f / sum;
        for (int i = 0; i < 16; ++i) lw[tid * 16 + i] *= inv;
    }
    __syncthreads();
    const int h = tid >> 5, d = tid & 31;
    const int starts[4] = {0, 15200, 19000, 19950};
    const int Wi[4] = {152, 76, 38, 19};
    const int Hi[4] = {100, 50, 25, 13};
    float a = 0.f;
#pragma unroll
    for (int l = 0; l < 4; ++l) {
        const int base = b * S_N + starts[l];
#pragma unroll
        for (int p = 0; p < 4; ++p) {
            int jj = h * 16 + l * 4 + p;
            float w  = lw[jj];
            float px = lx[jj] * Wf[l] - 0.5f;
            float py = ly[jj] * Hf[l] - 0.5f;
            float x0f = floorf(px), y0f = floorf(py);
            float fx = px - x0f, fy = py - y0f;
            int x0 = (int)x0f, y0 = (int)y0f;
#pragma unroll
            for (int dy = 0; dy < 2; ++dy) {
#pragma unroll
                for (int dx = 0; dx < 2; ++dx) {
                    int xi = x0 + dx, yi = y0 + dy;
                    float cw = (dx ? fx : 1.f - fx) * (dy ? fy : 1.f - fy);
                    bool valid = (xi >= 0) & (xi < Wi[l]) & (yi >= 0) & (yi < Hi[l]);
                    int xc = min(max(xi, 0), Wi[l] - 1);
                    int yc = min(max(yi, 0), Hi[l] - 1);
                    float g = value[(((size_t)(base + yc * Wi[l] + xc)) * 8 + h) * 32 + d];
                    a = fmaf(valid ? w * cw : 0.f, g, a);
                }
            }
        }
    }
    acc[(size_t)q * 256 + tid] = a;
}

// ---------------------------------------------------------------------------
// out[row] = LayerNorm(out[row] + X[row]) * g + b   (one block per row, D=256)
// ---------------------------------------------------------------------------
__global__ __launch_bounds__(256) void resid_ln_kernel(
    const float* __restrict__ X, float* __restrict__ out,
    const float* __restrict__ g, const float* __restrict__ beta)
{
    const int row = blockIdx.x;
    const int c = threadIdx.x;
    size_t idx = (size_t)row * 256 + c;
    float v = out[idx] + X[idx];
    float s = v;
#pragma unroll
    for (int o = 32; o >= 1; o >>= 1) s += __shfl_xor(s, o, 64);
    __shared__ float w1[4], w2[4];
    if ((c & 63) == 0) w1[c >> 6] = s;
    __syncthreads();
    float mean = (w1[0] + w1[1] + w1[2] + w1[3]) * (1.f / 256.f);
    float dd = v - mean;
    float sq = dd * dd;
#pragma unroll
    for (int o = 32; o >= 1; o >>= 1) sq += __shfl_xor(sq, o, 64);
    if ((c & 63) == 0) w2[c >> 6] = sq;
    __syncthreads();
    float var = (w2[0] + w2[1] + w2[2] + w2[3]) * (1.f / 256.f);
    out[idx] = dd * rsqrtf(var + 1e-5f) * g[c] + beta[c];
}

// ---------------------------------------------------------------------------
extern "C" void kernel_launch(void* const* d_in, const int* in_sizes, int n_in,
                              void* d_out, int out_size, void* d_ws, size_t ws_size,
                              hipStream_t stream)
{
    const float* src  = (const float*)d_in[0];
    const float* pos  = (const float*)d_in[1];
    const float* vr   = (const float*)d_in[2];
    const float* Wv   = (const float*)d_in[3];
    const float* bv   = (const float*)d_in[4];
    const float* Woff = (const float*)d_in[5];
    const float* boff = (const float*)d_in[6];
    const float* Wa   = (const float*)d_in[7];
    const float* ba   = (const float*)d_in[8];
    const float* Wo   = (const float*)d_in[9];
    const float* bo   = (const float*)d_in[10];
    const float* g1   = (const float*)d_in[11];
    const float* be1  = (const float*)d_in[12];
    const float* W1   = (const float*)d_in[13];
    const float* b1   = (const float*)d_in[14];
    const float* W2   = (const float*)d_in[15];
    const float* b2   = (const float*)d_in[16];
    const float* g2   = (const float*)d_in[17];
    const float* be2  = (const float*)d_in[18];

    float* out = (float*)d_out;
    float* ws  = (float*)d_ws;
    // Lean workspace layout (floats), total ~146 MB:
    //   refpts  323,200
    //   value   10,340,864  (also FFN hidden chunk buffer, CHUNK_ROWS*1024 <= this)
    //   offb    10,340,864  (also attn_out after sampler consumes it)
    //   alog     5,170,432
    //   accb    10,340,864  (sampler out; also FFN output)
    float* refpts = ws;
    float* value  = refpts + 323200;
    float* offb   = value  + 10340864;
    float* alog   = offb   + 10340864;
    float* accb   = alog   + 5170432;
    float* hbuf   = value;   // alias: value is dead once sampler has run
    float* attnb  = offb;    // alias: offb is dead once sampler has run
    float* ffnb   = accb;    // alias: accb is dead once Wo GEMM has run

    hipMemcpyAsync(out, src, (size_t)M_N * D_N * sizeof(float),
                   hipMemcpyDeviceToDevice, stream);
    compute_ref_kernel<<<(M_N + 255) / 256, 256, 0, stream>>>(vr, refpts);

    dim3 blk(256);
    const int mt = (M_N + 63) / 64;   // 632 row-tiles
    for (int i = 0; i < 6; ++i) {
        // value = out @ Wv + bv
        gemm_f32<<<dim3(mt, 4), blk, 0, stream>>>(out, nullptr, Wv + (size_t)i * 65536,
                                                  bv + i * 256, value, M_N, 256, 256, 0);
        // off   = (out+pos) @ Woff + boff
        gemm_f32<<<dim3(mt, 4), blk, 0, stream>>>(out, pos, Woff + (size_t)i * 65536,
                                                  boff + i * 256, offb, M_N, 256, 256, 0);
        // alog  = (out+pos) @ Wa + ba  (softmax deferred to sampler)
        gemm_f32<<<dim3(mt, 2), blk, 0, stream>>>(out, pos, Wa + (size_t)i * 32768,
                                                  ba + i * 128, alog, M_N, 128, 256, 0);
        // bilinear sampling + attention-weighted accumulate
        msda_sample_kernel<<<M_N, blk, 0, stream>>>(value, offb, alog, refpts, accb);
        // attn_out = acc @ Wo + bo   (into offb region; value/offb now dead)
        gemm_f32<<<dim3(mt, 4), blk, 0, stream>>>(accb, nullptr, Wo + (size_t)i * 65536,
                                                  bo + i * 256, attnb, M_N, 256, 256, 0);
        // out = LN(out + attn_out)
        resid_ln_kernel<<<M_N, blk, 0, stream>>>(attnb, out, g1 + i * 256, be1 + i * 256);
        // FFN, chunked over rows so hidden buffer fits in the value region
        for (int r0 = 0; r0 < M_N; r0 += CHUNK_ROWS) {
            int rows = min(CHUNK_ROWS, M_N - r0);
            int cmt = (rows + 63) / 64;
            gemm_f32<<<dim3(cmt, 16), blk, 0, stream>>>(out + (size_t)r0 * 256, nullptr,
                                                        W1 + (size_t)i * 262144,
                                                        b1 + i * 1024, hbuf, rows, 1024, 256, 1);
            gemm_f32<<<dim3(cmt, 4), blk, 0, stream>>>(hbuf, nullptr,
                                                       W2 + (size_t)i * 262144,
                                                       b2 + i * 256, ffnb + (size_t)r0 * 256,
                                                       rows, 256, 1024, 0);
        }
        // out = LN(out + ffn_out)
        resid_ln_kernel<<<M_N, blk, 0, stream>>>(ffnb, out, g2 + i * 256, be2 + i * 256);
    }
}

// Round 3
// 4905.421 us; speedup vs baseline: 1.5978x; 1.5978x over previous
//
#include <hip/hip_runtime.h>
#include <math.h>

// Problem constants (fixed by reference)
#define B_N   2
#define S_N   20197
#define M_N   (B_N * S_N)   // 40394 rows
#define D_N   256
#define NH_N  8
#define HD_N  32
#define DFF_N 1024
#define CHUNK_ROWS 10048    // FFN row-chunk so hidden buf fits in value region

typedef __attribute__((ext_vector_type(8))) short short8;
typedef __attribute__((ext_vector_type(4))) float f32x4;

__device__ __forceinline__ unsigned short f2bf(float f)
{
    unsigned u = __builtin_bit_cast(unsigned, f);
    u += 0x7fffu + ((u >> 16) & 1u);      // round-to-nearest-even
    return (unsigned short)(u >> 16);
}

// ---------------------------------------------------------------------------
// Reference points: ref[b,s,l,{x,y}]  (B,S,NL,2)
// ---------------------------------------------------------------------------
__global__ void compute_ref_kernel(const float* __restrict__ vr, float* __restrict__ refpts)
{
    int q = blockIdx.x * blockDim.x + threadIdx.x;
    if (q >= M_N) return;
    int b = q / S_N;
    int s = q - b * S_N;
    const int Hs[4] = {100, 50, 25, 13};
    const int Ws[4] = {152, 76, 38, 19};
    int l0, i, j;
    if (s < 15200)      { l0 = 0; i = s / 152; j = s - i * 152; }
    else if (s < 19000) { int t = s - 15200; l0 = 1; i = t / 76; j = t - i * 76; }
    else if (s < 19950) { int t = s - 19000; l0 = 2; i = t / 38; j = t - i * 38; }
    else                { int t = s - 19950; l0 = 3; i = t / 19; j = t - i * 19; }
    float ry = (i + 0.5f) / (vr[(b * 4 + l0) * 2 + 1] * (float)Hs[l0]);
    float rx = (j + 0.5f) / (vr[(b * 4 + l0) * 2 + 0] * (float)Ws[l0]);
#pragma unroll
    for (int l = 0; l < 4; ++l) {
        refpts[(size_t)q * 8 + l * 2 + 0] = rx * vr[(b * 4 + l) * 2 + 0];
        refpts[(size_t)q * 8 + l * 2 + 1] = ry * vr[(b * 4 + l) * 2 + 1];
    }
}

// ---------------------------------------------------------------------------
// Weight prep: W[K][N] fp32 -> Wt[N][K] bf16.  blockIdx.z = layer.
// ---------------------------------------------------------------------------
__global__ __launch_bounds__(256) void transpose_w_kernel(
    const float* __restrict__ W, unsigned short* __restrict__ Wt, int K, int N)
{
    __shared__ float t[32][33];
    const float* Wl = W + (size_t)blockIdx.z * K * N;
    unsigned short* Wtl = Wt + (size_t)blockIdx.z * K * N;
    int n0 = blockIdx.x * 32, k0 = blockIdx.y * 32;
    int tx = threadIdx.x & 31, ty = threadIdx.x >> 5;   // 32 x 8
#pragma unroll
    for (int r = 0; r < 32; r += 8)
        t[ty + r][tx] = Wl[(size_t)(k0 + ty + r) * N + n0 + tx];
    __syncthreads();
#pragma unroll
    for (int r = 0; r < 32; r += 8)
        Wtl[(size_t)(n0 + ty + r) * K + k0 + tx] = f2bf(t[tx][ty + r]);
}

// ---------------------------------------------------------------------------
// bf16 MFMA GEMM: C[M,N] = (A (+A2)) @ W + bias, optional relu.
// A fp32 [M][K] (converted to bf16 during staging); Wt bf16 [N][K].
// 128x128 block tile, BK=64, 256 threads = 4 waves, each wave 64x64 via
// 4x4 grid of v_mfma_f32_16x16x32_bf16.  N,K multiples of 64 (N mult of 128).
// ---------------------------------------------------------------------------
__global__ __launch_bounds__(256) void gemm_bf16(
    const float* __restrict__ A, const float* __restrict__ A2,
    const unsigned short* __restrict__ Wt, const float* __restrict__ bias,
    float* __restrict__ C, int M, int N, int K, int dorelu)
{
    __shared__ short As[128 * 72];   // [m][k], stride 72 (pad 8) -> 2-way max
    __shared__ short Bs[128 * 72];   // [n][k], stride 72
    const int tid  = threadIdx.x;
    const int m0   = blockIdx.x * 128, n0 = blockIdx.y * 128;
    const int lane = tid & 63, wave = tid >> 6;
    const int wm   = (wave & 1) * 64, wn = (wave >> 1) * 64;
    const int quad = lane >> 4, lm = lane & 15;

    f32x4 acc[4][4] = {};

    const int ar = tid >> 1, ac = (tid & 1) * 32;   // A stage: row, k-offset
    const int gm = m0 + ar;

    for (int k0 = 0; k0 < K; k0 += 64) {
        // ---- stage A (fp32 -> bf16), 32 elems/thread ----
        {
            short s[32];
            if (gm < M) {
                const float* ap = A + (size_t)gm * K + k0 + ac;
                if (A2) {
                    const float* pp = A2 + (size_t)gm * K + k0 + ac;
#pragma unroll
                    for (int i = 0; i < 8; ++i) {
                        f32x4 v = *(const f32x4*)(ap + 4 * i);
                        f32x4 p = *(const f32x4*)(pp + 4 * i);
                        v += p;
#pragma unroll
                        for (int j = 0; j < 4; ++j) s[i * 4 + j] = (short)f2bf(v[j]);
                    }
                } else {
#pragma unroll
                    for (int i = 0; i < 8; ++i) {
                        f32x4 v = *(const f32x4*)(ap + 4 * i);
#pragma unroll
                        for (int j = 0; j < 4; ++j) s[i * 4 + j] = (short)f2bf(v[j]);
                    }
                }
            } else {
#pragma unroll
                for (int i = 0; i < 32; ++i) s[i] = 0;
            }
            short* d = &As[ar * 72 + ac];
#pragma unroll
            for (int i = 0; i < 4; ++i) *(short8*)(d + i * 8) = *(short8*)(s + i * 8);
        }
        // ---- stage B (bf16 copy), 32 elems/thread ----
        {
            const unsigned short* wp = Wt + (size_t)(n0 + ar) * K + k0 + ac;
            short* d = &Bs[ar * 72 + ac];
#pragma unroll
            for (int i = 0; i < 4; ++i) *(short8*)(d + i * 8) = *(const short8*)(wp + i * 8);
        }
        __syncthreads();
        // ---- MFMA: 2 k-steps of 32 ----
#pragma unroll
        for (int ks = 0; ks < 2; ++ks) {
            short8 af[4], bf[4];
#pragma unroll
            for (int mi = 0; mi < 4; ++mi)
                af[mi] = *(short8*)&As[(wm + mi * 16 + lm) * 72 + ks * 32 + quad * 8];
#pragma unroll
            for (int ni = 0; ni < 4; ++ni)
                bf[ni] = *(short8*)&Bs[(wn + ni * 16 + lm) * 72 + ks * 32 + quad * 8];
#pragma unroll
            for (int mi = 0; mi < 4; ++mi)
#pragma unroll
                for (int ni = 0; ni < 4; ++ni)
                    acc[mi][ni] = __builtin_amdgcn_mfma_f32_16x16x32_bf16(
                        af[mi], bf[ni], acc[mi][ni], 0, 0, 0);
        }
        __syncthreads();
    }
    // ---- epilogue: C/D layout col=lane&15, row=quad*4+reg ----
#pragma unroll
    for (int ni = 0; ni < 4; ++ni) {
        int gc = n0 + wn + ni * 16 + lm;
        float bb = bias[gc];
#pragma unroll
        for (int mi = 0; mi < 4; ++mi) {
#pragma unroll
            for (int j = 0; j < 4; ++j) {
                int gr = m0 + wm + mi * 16 + quad * 4 + j;
                if (gr < M) {
                    float v = acc[mi][ni][j] + bb;
                    if (dorelu) v = fmaxf(v, 0.f);
                    C[(size_t)gr * N + gc] = v;
                }
            }
        }
    }
}

// ---------------------------------------------------------------------------
// MSDA sampling: one block per query. Threads = 8 heads x 32 channels.
// ---------------------------------------------------------------------------
__global__ __launch_bounds__(256) void msda_sample_kernel(
    const float* __restrict__ value,   // (B,S,NH,HD)
    const float* __restrict__ offb,    // (B,S,256) = (h,l,p,2)
    const float* __restrict__ alog,    // (B,S,128) = (h, l*4+p) raw logits
    const float* __restrict__ refpts,  // (B,S,NL,2)
    float* __restrict__ acc)           // (B,S,256) = (h,d)
{
    const int q = blockIdx.x;
    const int b = q / S_N;
    const int tid = threadIdx.x;
    __shared__ float lx[128], ly[128], lw[128];
    const float Wf[4] = {152.f, 76.f, 38.f, 19.f};
    const float Hf[4] = {100.f, 50.f, 25.f, 13.f};
    if (tid < 128) {
        int l = (tid >> 2) & 3;
        float ox = offb[(size_t)q * 256 + tid * 2 + 0];
        float oy = offb[(size_t)q * 256 + tid * 2 + 1];
        lx[tid] = refpts[(size_t)q * 8 + l * 2 + 0] + ox / Wf[l];
        ly[tid] = refpts[(size_t)q * 8 + l * 2 + 1] + oy / Hf[l];
        lw[tid] = alog[(size_t)q * 128 + tid];
    }
    __syncthreads();
    if (tid < 8) {
        float mx = -1e30f;
        for (int i = 0; i < 16; ++i) mx = fmaxf(mx, lw[tid * 16 + i]);
        float sum = 0.f;
        for (int i = 0; i < 16; ++i) {
            float e = expf(lw[tid * 16 + i] - mx);
            lw[tid * 16 + i] = e; sum += e;
        }
        float inv = 1.f / sum;
        for (int i = 0; i < 16; ++i) lw[tid * 16 + i] *= inv;
    }
    __syncthreads();
    const int h = tid >> 5, d = tid & 31;
    const int starts[4] = {0, 15200, 19000, 19950};
    const int Wi[4] = {152, 76, 38, 19};
    const int Hi[4] = {100, 50, 25, 13};
    float a = 0.f;
#pragma unroll
    for (int l = 0; l < 4; ++l) {
        const int base = b * S_N + starts[l];
#pragma unroll
        for (int p = 0; p < 4; ++p) {
            int jj = h * 16 + l * 4 + p;
            float w  = lw[jj];
            float px = lx[jj] * Wf[l] - 0.5f;
            float py = ly[jj] * Hf[l] - 0.5f;
            float x0f = floorf(px), y0f = floorf(py);
            float fx = px - x0f, fy = py - y0f;
            int x0 = (int)x0f, y0 = (int)y0f;
#pragma unroll
            for (int dy = 0; dy < 2; ++dy) {
#pragma unroll
                for (int dx = 0; dx < 2; ++dx) {
                    int xi = x0 + dx, yi = y0 + dy;
                    float cw = (dx ? fx : 1.f - fx) * (dy ? fy : 1.f - fy);
                    bool valid = (xi >= 0) & (xi < Wi[l]) & (yi >= 0) & (yi < Hi[l]);
                    int xc = min(max(xi, 0), Wi[l] - 1);
                    int yc = min(max(yi, 0), Hi[l] - 1);
                    float g = value[(((size_t)(base + yc * Wi[l] + xc)) * 8 + h) * 32 + d];
                    a = fmaf(valid ? w * cw : 0.f, g, a);
                }
            }
        }
    }
    acc[(size_t)q * 256 + tid] = a;
}

// ---------------------------------------------------------------------------
// out[row] = LayerNorm(out[row] + X[row]) * g + b   (one block per row, D=256)
// ---------------------------------------------------------------------------
__global__ __launch_bounds__(256) void resid_ln_kernel(
    const float* __restrict__ X, float* __restrict__ out,
    const float* __restrict__ g, const float* __restrict__ beta)
{
    const int row = blockIdx.x;
    const int c = threadIdx.x;
    size_t idx = (size_t)row * 256 + c;
    float v = out[idx] + X[idx];
    float s = v;
#pragma unroll
    for (int o = 32; o >= 1; o >>= 1) s += __shfl_xor(s, o, 64);
    __shared__ float w1[4], w2[4];
    if ((c & 63) == 0) w1[c >> 6] = s;
    __syncthreads();
    float mean = (w1[0] + w1[1] + w1[2] + w1[3]) * (1.f / 256.f);
    float dd = v - mean;
    float sq = dd * dd;
#pragma unroll
    for (int o = 32; o >= 1; o >>= 1) sq += __shfl_xor(sq, o, 64);
    if ((c & 63) == 0) w2[c >> 6] = sq;
    __syncthreads();
    float var = (w2[0] + w2[1] + w2[2] + w2[3]) * (1.f / 256.f);
    out[idx] = dd * rsqrtf(var + 1e-5f) * g[c] + beta[c];
}

// ---------------------------------------------------------------------------
extern "C" void kernel_launch(void* const* d_in, const int* in_sizes, int n_in,
                              void* d_out, int out_size, void* d_ws, size_t ws_size,
                              hipStream_t stream)
{
    const float* src  = (const float*)d_in[0];
    const float* pos  = (const float*)d_in[1];
    const float* vr   = (const float*)d_in[2];
    const float* Wv   = (const float*)d_in[3];
    const float* bv   = (const float*)d_in[4];
    const float* Woff = (const float*)d_in[5];
    const float* boff = (const float*)d_in[6];
    const float* Wa   = (const float*)d_in[7];
    const float* ba   = (const float*)d_in[8];
    const float* Wo   = (const float*)d_in[9];
    const float* bo   = (const float*)d_in[10];
    const float* g1   = (const float*)d_in[11];
    const float* be1  = (const float*)d_in[12];
    const float* W1   = (const float*)d_in[13];
    const float* b1   = (const float*)d_in[14];
    const float* W2   = (const float*)d_in[15];
    const float* b2   = (const float*)d_in[16];
    const float* g2   = (const float*)d_in[17];
    const float* be2  = (const float*)d_in[18];

    float* out = (float*)d_out;
    float* ws  = (float*)d_ws;
    // Workspace (floats): ~146 MB fp32 buffers + 9 MB bf16 weights
    float* refpts = ws;
    float* value  = refpts + 323200;
    float* offb   = value  + 10340864;
    float* alog   = offb   + 10340864;
    float* accb   = alog   + 5170432;
    float* hbuf   = value;   // alias: value dead once sampler has run
    float* attnb  = offb;    // alias: offb dead once sampler has run
    float* ffnb   = accb;    // alias: accb dead once Wo GEMM has run
    unsigned short* wtv   = (unsigned short*)(accb + 10340864);
    unsigned short* wtoff = wtv   + 6 * 65536;
    unsigned short* wta   = wtoff + 6 * 65536;
    unsigned short* wto   = wta   + 6 * 32768;
    unsigned short* wt1   = wto   + 6 * 65536;
    unsigned short* wt2   = wt1   + 6 * 262144;

    hipMemcpyAsync(out, src, (size_t)M_N * D_N * sizeof(float),
                   hipMemcpyDeviceToDevice, stream);
    compute_ref_kernel<<<(M_N + 255) / 256, 256, 0, stream>>>(vr, refpts);

    dim3 blk(256);
    // Weight prep: fp32 [K][N] -> bf16 [N][K], all 6 layers per launch
    transpose_w_kernel<<<dim3(8, 8, 6),  blk, 0, stream>>>(Wv,   wtv,   256, 256);
    transpose_w_kernel<<<dim3(8, 8, 6),  blk, 0, stream>>>(Woff, wtoff, 256, 256);
    transpose_w_kernel<<<dim3(4, 8, 6),  blk, 0, stream>>>(Wa,   wta,   256, 128);
    transpose_w_kernel<<<dim3(8, 8, 6),  blk, 0, stream>>>(Wo,   wto,   256, 256);
    transpose_w_kernel<<<dim3(32, 8, 6), blk, 0, stream>>>(W1,   wt1,   256, 1024);
    transpose_w_kernel<<<dim3(8, 32, 6), blk, 0, stream>>>(W2,   wt2,   1024, 256);

    const int mt = (M_N + 127) / 128;   // 316 row-tiles
    for (int i = 0; i < 6; ++i) {
        // value = out @ Wv + bv
        gemm_bf16<<<dim3(mt, 2), blk, 0, stream>>>(out, nullptr, wtv + (size_t)i * 65536,
                                                   bv + i * 256, value, M_N, 256, 256, 0);
        // off = (out+pos) @ Woff + boff
        gemm_bf16<<<dim3(mt, 2), blk, 0, stream>>>(out, pos, wtoff + (size_t)i * 65536,
                                                   boff + i * 256, offb, M_N, 256, 256, 0);
        // alog = (out+pos) @ Wa + ba
        gemm_bf16<<<dim3(mt, 1), blk, 0, stream>>>(out, pos, wta + (size_t)i * 32768,
                                                   ba + i * 128, alog, M_N, 128, 256, 0);
        // bilinear sampling + attention-weighted accumulate
        msda_sample_kernel<<<M_N, blk, 0, stream>>>(value, offb, alog, refpts, accb);
        // attn_out = acc @ Wo + bo  (into offb region)
        gemm_bf16<<<dim3(mt, 2), blk, 0, stream>>>(accb, nullptr, wto + (size_t)i * 65536,
                                                   bo + i * 256, attnb, M_N, 256, 256, 0);
        // out = LN(out + attn_out)
        resid_ln_kernel<<<M_N, blk, 0, stream>>>(attnb, out, g1 + i * 256, be1 + i * 256);
        // FFN, chunked so hidden buffer fits in the value region
        for (int r0 = 0; r0 < M_N; r0 += CHUNK_ROWS) {
            int rows = min(CHUNK_ROWS, M_N - r0);
            int cmt = (rows + 127) / 128;
            gemm_bf16<<<dim3(cmt, 8), blk, 0, stream>>>(out + (size_t)r0 * 256, nullptr,
                                                        wt1 + (size_t)i * 262144,
                                                        b1 + i * 1024, hbuf, rows, 1024, 256, 1);
            gemm_bf16<<<dim3(cmt, 2), blk, 0, stream>>>(hbuf, nullptr,
                                                        wt2 + (size_t)i * 262144,
                                                        b2 + i * 256, ffnb + (size_t)r0 * 256,
                                                        rows, 256, 1024, 0);
        }
        // out = LN(out + ffn_out)
        resid_ln_kernel<<<M_N, blk, 0, stream>>>(ffnb, out, g2 + i * 256, be2 + i * 256);
    }
}

// Round 4
// 3583.363 us; speedup vs baseline: 2.1873x; 1.3689x over previous
//
#include <hip/hip_runtime.h>
#include <math.h>

// Problem constants (fixed by reference)
#define B_N   2
#define S_N   20197
#define M_N   (B_N * S_N)   // 40394 rows
#define D_N   256
#define NH_N  8
#define HD_N  32
#define DFF_N 1024
#define CHUNK_ROWS 10048    // FFN row-chunk: bf16 hidden fits in value-region first half

typedef __attribute__((ext_vector_type(8))) short short8;
typedef __attribute__((ext_vector_type(4))) float f32x4;

__device__ __forceinline__ unsigned short f2bf(float f)
{
    unsigned u = __builtin_bit_cast(unsigned, f);
    u += 0x7fffu + ((u >> 16) & 1u);      // round-to-nearest-even
    return (unsigned short)(u >> 16);
}

// ---------------------------------------------------------------------------
// Reference points: ref[b,s,l,{x,y}]  (B,S,NL,2)
// ---------------------------------------------------------------------------
__global__ void compute_ref_kernel(const float* __restrict__ vr, float* __restrict__ refpts)
{
    int q = blockIdx.x * blockDim.x + threadIdx.x;
    if (q >= M_N) return;
    int b = q / S_N;
    int s = q - b * S_N;
    const int Hs[4] = {100, 50, 25, 13};
    const int Ws[4] = {152, 76, 38, 19};
    int l0, i, j;
    if (s < 15200)      { l0 = 0; i = s / 152; j = s - i * 152; }
    else if (s < 19000) { int t = s - 15200; l0 = 1; i = t / 76; j = t - i * 76; }
    else if (s < 19950) { int t = s - 19000; l0 = 2; i = t / 38; j = t - i * 38; }
    else                { int t = s - 19950; l0 = 3; i = t / 19; j = t - i * 19; }
    float ry = (i + 0.5f) / (vr[(b * 4 + l0) * 2 + 1] * (float)Hs[l0]);
    float rx = (j + 0.5f) / (vr[(b * 4 + l0) * 2 + 0] * (float)Ws[l0]);
#pragma unroll
    for (int l = 0; l < 4; ++l) {
        refpts[(size_t)q * 8 + l * 2 + 0] = rx * vr[(b * 4 + l) * 2 + 0];
        refpts[(size_t)q * 8 + l * 2 + 1] = ry * vr[(b * 4 + l) * 2 + 1];
    }
}

// ---------------------------------------------------------------------------
// Weight prep: W[K][N] fp32 -> Wt[N][K] bf16.  blockIdx.z = layer.
// ---------------------------------------------------------------------------
__global__ __launch_bounds__(256) void transpose_w_kernel(
    const float* __restrict__ W, unsigned short* __restrict__ Wt, int K, int N)
{
    __shared__ float t[32][33];
    const float* Wl = W + (size_t)blockIdx.z * K * N;
    unsigned short* Wtl = Wt + (size_t)blockIdx.z * K * N;
    int n0 = blockIdx.x * 32, k0 = blockIdx.y * 32;
    int tx = threadIdx.x & 31, ty = threadIdx.x >> 5;   // 32 x 8
#pragma unroll
    for (int r = 0; r < 32; r += 8)
        t[ty + r][tx] = Wl[(size_t)(k0 + ty + r) * N + n0 + tx];
    __syncthreads();
#pragma unroll
    for (int r = 0; r < 32; r += 8)
        Wtl[(size_t)(n0 + ty + r) * K + k0 + tx] = f2bf(t[tx][ty + r]);
}

// ---------------------------------------------------------------------------
// init: out = src; outb = bf16(src); qb = bf16(src + pos)
// ---------------------------------------------------------------------------
__global__ __launch_bounds__(256) void init_kernel(
    const float* __restrict__ src, const float* __restrict__ pos,
    float* __restrict__ out, unsigned short* __restrict__ outb,
    unsigned short* __restrict__ qb)
{
    size_t i = (size_t)blockIdx.x * 256 + threadIdx.x;
    float s = src[i];
    out[i]  = s;
    outb[i] = f2bf(s);
    qb[i]   = f2bf(s + pos[i]);
}

// ---------------------------------------------------------------------------
// bf16 MFMA GEMM: C[M,N] = A @ Wt^T + bias.
// A bf16 [M][K]; Wt bf16 [N][K].  128x128 tile, BK=64, 4 waves, 4x4 MFMA each.
// mode: 0 = fp32 out, 1 = bf16 out, 2 = bf16 out + relu
// ---------------------------------------------------------------------------
__global__ __launch_bounds__(256) void gemm_bf16(
    const unsigned short* __restrict__ A, const unsigned short* __restrict__ Wt,
    const float* __restrict__ bias, void* __restrict__ Cv,
    int M, int N, int K, int mode)
{
    __shared__ short As[128 * 72];   // [m][k], stride 72 (pad 8 shorts)
    __shared__ short Bs[128 * 72];   // [n][k]
    const int tid  = threadIdx.x;
    const int m0   = blockIdx.x * 128, n0 = blockIdx.y * 128;
    const int lane = tid & 63, wave = tid >> 6;
    const int wm   = (wave & 1) * 64, wn = (wave >> 1) * 64;
    const int quad = lane >> 4, lm = lane & 15;

    f32x4 acc[4][4] = {};

    const int ar = tid >> 1, ac = (tid & 1) * 32;
    const int gm = m0 + ar;

    for (int k0 = 0; k0 < K; k0 += 64) {
        short8 s[4];
        if (gm < M) {
            const unsigned short* ap = A + (size_t)gm * K + k0 + ac;
#pragma unroll
            for (int i = 0; i < 4; ++i) s[i] = *(const short8*)(ap + 8 * i);
        } else {
#pragma unroll
            for (int i = 0; i < 4; ++i) s[i] = short8{0,0,0,0,0,0,0,0};
        }
        short* da = &As[ar * 72 + ac];
#pragma unroll
        for (int i = 0; i < 4; ++i) *(short8*)(da + i * 8) = s[i];

        const unsigned short* wp = Wt + (size_t)(n0 + ar) * K + k0 + ac;
        short* db = &Bs[ar * 72 + ac];
#pragma unroll
        for (int i = 0; i < 4; ++i) *(short8*)(db + i * 8) = *(const short8*)(wp + i * 8);
        __syncthreads();
#pragma unroll
        for (int ks = 0; ks < 2; ++ks) {
            short8 af[4], bf[4];
#pragma unroll
            for (int mi = 0; mi < 4; ++mi)
                af[mi] = *(short8*)&As[(wm + mi * 16 + lm) * 72 + ks * 32 + quad * 8];
#pragma unroll
            for (int ni = 0; ni < 4; ++ni)
                bf[ni] = *(short8*)&Bs[(wn + ni * 16 + lm) * 72 + ks * 32 + quad * 8];
#pragma unroll
            for (int mi = 0; mi < 4; ++mi)
#pragma unroll
                for (int ni = 0; ni < 4; ++ni)
                    acc[mi][ni] = __builtin_amdgcn_mfma_f32_16x16x32_bf16(
                        af[mi], bf[ni], acc[mi][ni], 0, 0, 0);
        }
        __syncthreads();
    }
    // epilogue: C/D layout col=lane&15, row=quad*4+reg
    if (mode == 0) {
        float* C = (float*)Cv;
#pragma unroll
        for (int ni = 0; ni < 4; ++ni) {
            int gc = n0 + wn + ni * 16 + lm;
            float bb = bias[gc];
#pragma unroll
            for (int mi = 0; mi < 4; ++mi)
#pragma unroll
                for (int j = 0; j < 4; ++j) {
                    int gr = m0 + wm + mi * 16 + quad * 4 + j;
                    if (gr < M) C[(size_t)gr * N + gc] = acc[mi][ni][j] + bb;
                }
        }
    } else {
        unsigned short* C = (unsigned short*)Cv;
        const bool dorelu = (mode == 2);
#pragma unroll
        for (int ni = 0; ni < 4; ++ni) {
            int gc = n0 + wn + ni * 16 + lm;
            float bb = bias[gc];
#pragma unroll
            for (int mi = 0; mi < 4; ++mi)
#pragma unroll
                for (int j = 0; j < 4; ++j) {
                    int gr = m0 + wm + mi * 16 + quad * 4 + j;
                    if (gr < M) {
                        float v = acc[mi][ni][j] + bb;
                        if (dorelu) v = fmaxf(v, 0.f);
                        C[(size_t)gr * N + gc] = f2bf(v);
                    }
                }
        }
    }
}

// ---------------------------------------------------------------------------
// MSDA sampler v2: 2 queries / block.
// Phase 1 (256 thr = 2q x 128 pts): softmax via shuffles, bilinear corner
//   offsets+weights -> LDS.  Phase 2: gather bf16 value pairs + fma only.
// ---------------------------------------------------------------------------
__global__ __launch_bounds__(256) void msda_sample_kernel(
    const unsigned short* __restrict__ value,  // bf16 (B,S,NH,HD)
    const float* __restrict__ offb,            // fp32 (B,S,256)
    const float* __restrict__ alog,            // fp32 (B,S,128)
    const float* __restrict__ refpts,          // fp32 (B,S,NL,2)
    unsigned short* __restrict__ accb)         // bf16 (B,S,256)
{
    __shared__ __align__(16) int pts[256][4][2];   // [pt][corner][{byteoff,w}]
    const int tid = threadIdx.x;
    const int q0 = blockIdx.x * 2;
    {
        const int q  = q0 + (tid >> 7);
        const int jj = tid & 127;
        const int h  = jj >> 4, l = (jj >> 2) & 3;
        const int b  = q / S_N;
        const int Wi = 152 >> l;
        const int Hi = (100 >> l) + (l == 3);
        const float Wf = (float)Wi, Hf = (float)Hi;
        const int start = (l < 1) ? 0 : (l < 2) ? 15200 : (l < 3) ? 19000 : 19950;
        float2 off2 = *(const float2*)(offb + (size_t)q * 256 + jj * 2);
        float2 rp   = *(const float2*)(refpts + (size_t)q * 8 + l * 2);
        float logit = alog[(size_t)q * 128 + jj];
        float mx = logit;
#pragma unroll
        for (int o = 1; o < 16; o <<= 1) mx = fmaxf(mx, __shfl_xor(mx, o, 64));
        float e = expf(logit - mx);
        float sum = e;
#pragma unroll
        for (int o = 1; o < 16; o <<= 1) sum += __shfl_xor(sum, o, 64);
        float w = e / sum;
        float px = (rp.x + off2.x / Wf) * Wf - 0.5f;
        float py = (rp.y + off2.y / Hf) * Hf - 0.5f;
        float x0f = floorf(px), y0f = floorf(py);
        float fx = px - x0f, fy = py - y0f;
        int x0 = (int)x0f, y0 = (int)y0f;
        int base = b * S_N + start;
#pragma unroll
        for (int c = 0; c < 4; ++c) {
            int dx = c & 1, dy = c >> 1;
            int xi = x0 + dx, yi = y0 + dy;
            bool valid = (xi >= 0) & (xi < Wi) & (yi >= 0) & (yi < Hi);
            int xc = min(max(xi, 0), Wi - 1);
            int yc = min(max(yi, 0), Hi - 1);
            float cw = (dx ? fx : 1.f - fx) * (dy ? fy : 1.f - fy);
            int offby = ((base + yc * Wi + xc) * 256 + h * 32) * 2;  // bf16 bytes
            float wc = valid ? w * cw : 0.f;
            pts[tid][c][0] = offby;
            pts[tid][c][1] = __builtin_bit_cast(int, wc);
        }
    }
    __syncthreads();
    const int qq = tid >> 7;
    const int g  = tid & 127;
    const int hh = g >> 4;
    const int dd = (g & 15) * 2;            // channel pair
    const char* vb = (const char*)value + dd * 2;
    float a0 = 0.f, a1 = 0.f;
    const int p0 = qq * 128 + hh * 16;
#pragma unroll
    for (int t = 0; t < 16; ++t) {
        int4 c01 = *(const int4*)&pts[p0 + t][0][0];
        int4 c23 = *(const int4*)&pts[p0 + t][2][0];
        {
            unsigned ld = *(const unsigned*)(vb + c01.x);
            float w = __builtin_bit_cast(float, c01.y);
            a0 = fmaf(w, __builtin_bit_cast(float, ld << 16), a0);
            a1 = fmaf(w, __builtin_bit_cast(float, ld & 0xffff0000u), a1);
        }
        {
            unsigned ld = *(const unsigned*)(vb + c01.z);
            float w = __builtin_bit_cast(float, c01.w);
            a0 = fmaf(w, __builtin_bit_cast(float, ld << 16), a0);
            a1 = fmaf(w, __builtin_bit_cast(float, ld & 0xffff0000u), a1);
        }
        {
            unsigned ld = *(const unsigned*)(vb + c23.x);
            float w = __builtin_bit_cast(float, c23.y);
            a0 = fmaf(w, __builtin_bit_cast(float, ld << 16), a0);
            a1 = fmaf(w, __builtin_bit_cast(float, ld & 0xffff0000u), a1);
        }
        {
            unsigned ld = *(const unsigned*)(vb + c23.z);
            float w = __builtin_bit_cast(float, c23.w);
            a0 = fmaf(w, __builtin_bit_cast(float, ld << 16), a0);
            a1 = fmaf(w, __builtin_bit_cast(float, ld & 0xffff0000u), a1);
        }
    }
    int q = q0 + qq;
    unsigned packed = (unsigned)f2bf(a0) | ((unsigned)f2bf(a1) << 16);
    *(unsigned*)((char*)accb + ((size_t)q * 256 + hh * 32 + dd) * 2) = packed;
}

// ---------------------------------------------------------------------------
// out = LN(out + X); outb = bf16(out); optional qb = bf16(out + pos)
// ---------------------------------------------------------------------------
__global__ __launch_bounds__(256) void resid_ln_kernel(
    const float* __restrict__ X, float* __restrict__ out,
    const float* __restrict__ g, const float* __restrict__ beta,
    unsigned short* __restrict__ outb,
    const float* __restrict__ pos, unsigned short* __restrict__ qb)
{
    const int row = blockIdx.x;
    const int c = threadIdx.x;
    size_t idx = (size_t)row * 256 + c;
    float v = out[idx] + X[idx];
    float s = v;
#pragma unroll
    for (int o = 32; o >= 1; o >>= 1) s += __shfl_xor(s, o, 64);
    __shared__ float w1[4], w2[4];
    if ((c & 63) == 0) w1[c >> 6] = s;
    __syncthreads();
    float mean = (w1[0] + w1[1] + w1[2] + w1[3]) * (1.f / 256.f);
    float dd = v - mean;
    float sq = dd * dd;
#pragma unroll
    for (int o = 32; o >= 1; o >>= 1) sq += __shfl_xor(sq, o, 64);
    if ((c & 63) == 0) w2[c >> 6] = sq;
    __syncthreads();
    float var = (w2[0] + w2[1] + w2[2] + w2[3]) * (1.f / 256.f);
    float r = dd * rsqrtf(var + 1e-5f) * g[c] + beta[c];
    out[idx]  = r;
    outb[idx] = f2bf(r);
    if (qb) qb[idx] = f2bf(r + pos[idx]);
}

// ---------------------------------------------------------------------------
extern "C" void kernel_launch(void* const* d_in, const int* in_sizes, int n_in,
                              void* d_out, int out_size, void* d_ws, size_t ws_size,
                              hipStream_t stream)
{
    const float* src  = (const float*)d_in[0];
    const float* pos  = (const float*)d_in[1];
    const float* vr   = (const float*)d_in[2];
    const float* Wv   = (const float*)d_in[3];
    const float* bv   = (const float*)d_in[4];
    const float* Woff = (const float*)d_in[5];
    const float* boff = (const float*)d_in[6];
    const float* Wa   = (const float*)d_in[7];
    const float* ba   = (const float*)d_in[8];
    const float* Wo   = (const float*)d_in[9];
    const float* bo   = (const float*)d_in[10];
    const float* g1   = (const float*)d_in[11];
    const float* be1  = (const float*)d_in[12];
    const float* W1   = (const float*)d_in[13];
    const float* b1   = (const float*)d_in[14];
    const float* W2   = (const float*)d_in[15];
    const float* b2   = (const float*)d_in[16];
    const float* g2   = (const float*)d_in[17];
    const float* be2  = (const float*)d_in[18];

    float* out = (float*)d_out;
    float* ws  = (float*)d_ws;
    // Regions (floats). ~146 MB + 9 MB bf16 weights — same footprint as round 3.
    // value region [10,340,864 f]: first half = qb -> value_bf -> hbuf (bf16,
    //   sequential lifetimes); tail (offset 5,170,432 f) = outb (bf16).
    // offb region: fp32 offsets; attnb after sampler.
    // accb region: accb_bf (bf16, first half) -> ffnb (fp32, full).
    float* refpts = ws;
    float* valreg = refpts + 323200;
    float* offb   = valreg + 10340864;
    float* alog   = offb   + 10340864;
    float* accreg = alog   + 5170432;
    unsigned short* qb       = (unsigned short*)valreg;
    unsigned short* value_bf = (unsigned short*)valreg;
    unsigned short* hbuf_bf  = (unsigned short*)valreg;
    unsigned short* outb     = (unsigned short*)(valreg + 5170432);
    float*          attnb    = offb;
    unsigned short* accb_bf  = (unsigned short*)accreg;
    float*          ffnb     = accreg;
    unsigned short* wtv   = (unsigned short*)(accreg + 10340864);
    unsigned short* wtoff = wtv   + 6 * 65536;
    unsigned short* wta   = wtoff + 6 * 65536;
    unsigned short* wto   = wta   + 6 * 32768;
    unsigned short* wt1   = wto   + 6 * 65536;
    unsigned short* wt2   = wt1   + 6 * 262144;

    dim3 blk(256);
    compute_ref_kernel<<<(M_N + 255) / 256, 256, 0, stream>>>(vr, refpts);
    init_kernel<<<M_N, blk, 0, stream>>>(src, pos, out, outb, qb);
    transpose_w_kernel<<<dim3(8, 8, 6),  blk, 0, stream>>>(Wv,   wtv,   256, 256);
    transpose_w_kernel<<<dim3(8, 8, 6),  blk, 0, stream>>>(Woff, wtoff, 256, 256);
    transpose_w_kernel<<<dim3(4, 8, 6),  blk, 0, stream>>>(Wa,   wta,   256, 128);
    transpose_w_kernel<<<dim3(8, 8, 6),  blk, 0, stream>>>(Wo,   wto,   256, 256);
    transpose_w_kernel<<<dim3(32, 8, 6), blk, 0, stream>>>(W1,   wt1,   256, 1024);
    transpose_w_kernel<<<dim3(8, 32, 6), blk, 0, stream>>>(W2,   wt2,   1024, 256);

    const int mt = (M_N + 127) / 128;   // 316
    for (int i = 0; i < 6; ++i) {
        // off/alog first (consume qb), then value GEMM overwrites qb region
        gemm_bf16<<<dim3(mt, 2), blk, 0, stream>>>(qb, wtoff + (size_t)i * 65536,
                                                   boff + i * 256, offb, M_N, 256, 256, 0);
        gemm_bf16<<<dim3(mt, 1), blk, 0, stream>>>(qb, wta + (size_t)i * 32768,
                                                   ba + i * 128, alog, M_N, 128, 256, 0);
        gemm_bf16<<<dim3(mt, 2), blk, 0, stream>>>(outb, wtv + (size_t)i * 65536,
                                                   bv + i * 256, value_bf, M_N, 256, 256, 1);
        msda_sample_kernel<<<M_N / 2, blk, 0, stream>>>(value_bf, offb, alog, refpts, accb_bf);
        gemm_bf16<<<dim3(mt, 2), blk, 0, stream>>>(accb_bf, wto + (size_t)i * 65536,
                                                   bo + i * 256, attnb, M_N, 256, 256, 0);
        resid_ln_kernel<<<M_N, blk, 0, stream>>>(attnb, out, g1 + i * 256, be1 + i * 256,
                                                 outb, nullptr, nullptr);
        for (int r0 = 0; r0 < M_N; r0 += CHUNK_ROWS) {
            int rows = min(CHUNK_ROWS, M_N - r0);
            int cmt = (rows + 127) / 128;
            gemm_bf16<<<dim3(cmt, 8), blk, 0, stream>>>(outb + (size_t)r0 * 256,
                                                        wt1 + (size_t)i * 262144,
                                                        b1 + i * 1024, hbuf_bf, rows, 1024, 256, 2);
            gemm_bf16<<<dim3(cmt, 2), blk, 0, stream>>>(hbuf_bf,
                                                        wt2 + (size_t)i * 262144,
                                                        b2 + i * 256, ffnb + (size_t)r0 * 256,
                                                        rows, 256, 1024, 0);
        }
        resid_ln_kernel<<<M_N, blk, 0, stream>>>(ffnb, out, g2 + i * 256, be2 + i * 256,
                                                 outb, pos, qb);
    }
}

// Round 5
// 2601.479 us; speedup vs baseline: 3.0128x; 1.3774x over previous
//
#include <hip/hip_runtime.h>
#include <math.h>

#define B_N   2
#define S_N   20197
#define M_N   (B_N * S_N)   // 40394 rows
#define D_N   256
#define NH_N  8
#define HD_N  32
#define DFF_N 1024

typedef __attribute__((ext_vector_type(8))) short short8;
typedef __attribute__((ext_vector_type(4))) float f32x4;

__device__ __forceinline__ unsigned short f2bf(float f)
{
    unsigned u = __builtin_bit_cast(unsigned, f);
    u += 0x7fffu + ((u >> 16) & 1u);
    return (unsigned short)(u >> 16);
}
__device__ __forceinline__ float bf2f(unsigned short s)
{
    return __builtin_bit_cast(float, ((unsigned)s) << 16);
}

// ---------------------------------------------------------------------------
// Reference points: ref[b,s,l,{x,y}]
// ---------------------------------------------------------------------------
__global__ void compute_ref_kernel(const float* __restrict__ vr, float* __restrict__ refpts)
{
    int q = blockIdx.x * blockDim.x + threadIdx.x;
    if (q >= M_N) return;
    int b = q / S_N;
    int s = q - b * S_N;
    const int Hs[4] = {100, 50, 25, 13};
    const int Ws[4] = {152, 76, 38, 19};
    int l0, i, j;
    if (s < 15200)      { l0 = 0; i = s / 152; j = s - i * 152; }
    else if (s < 19000) { int t = s - 15200; l0 = 1; i = t / 76; j = t - i * 76; }
    else if (s < 19950) { int t = s - 19000; l0 = 2; i = t / 38; j = t - i * 38; }
    else                { int t = s - 19950; l0 = 3; i = t / 19; j = t - i * 19; }
    float ry = (i + 0.5f) / (vr[(b * 4 + l0) * 2 + 1] * (float)Hs[l0]);
    float rx = (j + 0.5f) / (vr[(b * 4 + l0) * 2 + 0] * (float)Ws[l0]);
#pragma unroll
    for (int l = 0; l < 4; ++l) {
        refpts[(size_t)q * 8 + l * 2 + 0] = rx * vr[(b * 4 + l) * 2 + 0];
        refpts[(size_t)q * 8 + l * 2 + 1] = ry * vr[(b * 4 + l) * 2 + 1];
    }
}

// ---------------------------------------------------------------------------
// Weight prep: W[K][Nsrc] fp32 -> Wt[rowOff+n][K] bf16 (dst row-stride dstN)
// ---------------------------------------------------------------------------
__global__ __launch_bounds__(256) void transpose_w_kernel(
    const float* __restrict__ W, unsigned short* __restrict__ Wt,
    int K, int Nsrc, int dstN, int rowOff)
{
    __shared__ float t[32][33];
    const float* Wl = W + (size_t)blockIdx.z * K * Nsrc;
    unsigned short* Wtl = Wt + (size_t)blockIdx.z * K * dstN;
    int n0 = blockIdx.x * 32, k0 = blockIdx.y * 32;
    int tx = threadIdx.x & 31, ty = threadIdx.x >> 5;
#pragma unroll
    for (int r = 0; r < 32; r += 8)
        t[ty + r][tx] = Wl[(size_t)(k0 + ty + r) * Nsrc + n0 + tx];
    __syncthreads();
#pragma unroll
    for (int r = 0; r < 32; r += 8)
        Wtl[(size_t)(rowOff + n0 + ty + r) * K + k0 + tx] = f2bf(t[tx][ty + r]);
}

__global__ void boa_kernel(const float* __restrict__ boff, const float* __restrict__ ba,
                           float* __restrict__ boa)
{
    int i = blockIdx.x, j = threadIdx.x;   // 6 x 384
    boa[i * 384 + j] = (j < 256) ? boff[i * 256 + j] : ba[i * 128 + j - 256];
}

// init: out = src; outb = bf16(src); qb = bf16(src + pos)
__global__ __launch_bounds__(256) void init_kernel(
    const float* __restrict__ src, const float* __restrict__ pos,
    float* __restrict__ out, unsigned short* __restrict__ outb,
    unsigned short* __restrict__ qb)
{
    size_t i = (size_t)blockIdx.x * 256 + threadIdx.x;
    float s = src[i];
    out[i]  = s;
    outb[i] = f2bf(s);
    qb[i]   = f2bf(s + pos[i]);
}

// ---------------------------------------------------------------------------
// bf16 MFMA GEMM: C = A @ Wt^T + bias.  128x128 tile, BK=64.
// mode: 1 = bf16 out, 2 = bf16 out + relu
// ---------------------------------------------------------------------------
__global__ __launch_bounds__(256) void gemm_bf16(
    const unsigned short* __restrict__ A, const unsigned short* __restrict__ Wt,
    const float* __restrict__ bias, unsigned short* __restrict__ C,
    int M, int N, int K, int mode)
{
    __shared__ short As[128 * 72];
    __shared__ short Bs[128 * 72];
    const int tid  = threadIdx.x;
    const int m0   = blockIdx.x * 128, n0 = blockIdx.y * 128;
    const int lane = tid & 63, wave = tid >> 6;
    const int wm   = (wave & 1) * 64, wn = (wave >> 1) * 64;
    const int quad = lane >> 4, lm = lane & 15;
    f32x4 acc[4][4] = {};
    const int ar = tid >> 1, ac = (tid & 1) * 32;
    const int gm = m0 + ar;

    for (int k0 = 0; k0 < K; k0 += 64) {
        short8 s[4];
        if (gm < M) {
            const unsigned short* ap = A + (size_t)gm * K + k0 + ac;
#pragma unroll
            for (int i = 0; i < 4; ++i) s[i] = *(const short8*)(ap + 8 * i);
        } else {
#pragma unroll
            for (int i = 0; i < 4; ++i) s[i] = short8{0,0,0,0,0,0,0,0};
        }
        short* da = &As[ar * 72 + ac];
#pragma unroll
        for (int i = 0; i < 4; ++i) *(short8*)(da + i * 8) = s[i];
        const unsigned short* wp = Wt + (size_t)(n0 + ar) * K + k0 + ac;
        short* db = &Bs[ar * 72 + ac];
#pragma unroll
        for (int i = 0; i < 4; ++i) *(short8*)(db + i * 8) = *(const short8*)(wp + i * 8);
        __syncthreads();
#pragma unroll
        for (int ks = 0; ks < 2; ++ks) {
            short8 af[4], bf[4];
#pragma unroll
            for (int mi = 0; mi < 4; ++mi)
                af[mi] = *(short8*)&As[(wm + mi * 16 + lm) * 72 + ks * 32 + quad * 8];
#pragma unroll
            for (int ni = 0; ni < 4; ++ni)
                bf[ni] = *(short8*)&Bs[(wn + ni * 16 + lm) * 72 + ks * 32 + quad * 8];
#pragma unroll
            for (int mi = 0; mi < 4; ++mi)
#pragma unroll
                for (int ni = 0; ni < 4; ++ni)
                    acc[mi][ni] = __builtin_amdgcn_mfma_f32_16x16x32_bf16(
                        af[mi], bf[ni], acc[mi][ni], 0, 0, 0);
        }
        __syncthreads();
    }
    const bool dorelu = (mode == 2);
#pragma unroll
    for (int ni = 0; ni < 4; ++ni) {
        int gc = n0 + wn + ni * 16 + lm;
        float bb = bias[gc];
#pragma unroll
        for (int mi = 0; mi < 4; ++mi)
#pragma unroll
            for (int j = 0; j < 4; ++j) {
                int gr = m0 + wm + mi * 16 + quad * 4 + j;
                if (gr < M) {
                    float v = acc[mi][ni][j] + bb;
                    if (dorelu) v = fmaxf(v, 0.f);
                    C[(size_t)gr * N + gc] = f2bf(v);
                }
            }
    }
}

// ---------------------------------------------------------------------------
// Fused GEMM (N=256 full row) + residual + LayerNorm.
// C_row = A@Wt^T + bias;  out = LN(out + C_row)*g + beta;  outb = bf16(out);
// optional qb = bf16(out + pos).  Tile 128x256, 4 waves (2x2 of 64x128).
// ---------------------------------------------------------------------------
__global__ __launch_bounds__(256, 2) void gemm_bf16_ln(
    const unsigned short* __restrict__ A, const unsigned short* __restrict__ Wt,
    const float* __restrict__ bias, float* __restrict__ out,
    unsigned short* __restrict__ outb, const float* __restrict__ g,
    const float* __restrict__ beta, const float* __restrict__ pos,
    unsigned short* __restrict__ qb, int M, int K)
{
    __shared__ short As[128 * 72];
    __shared__ short Bs[256 * 72];
    __shared__ float red[128][4];     // [row][{s0,sq0,s1,sq1}]
    __shared__ float mstat[128][2];   // [row][{mean,rstd}]
    const int tid  = threadIdx.x;
    const int m0   = blockIdx.x * 128;
    const int lane = tid & 63, wave = tid >> 6;
    const int wm   = (wave & 1) * 64, wn = (wave >> 1) * 128;
    const int quad = lane >> 4, lm = lane & 15;
    f32x4 acc[4][8] = {};
    const int ar = tid >> 1, ac = (tid & 1) * 32;
    const int gm = m0 + ar;

    for (int k0 = 0; k0 < K; k0 += 64) {
        short8 s[4];
        if (gm < M) {
            const unsigned short* ap = A + (size_t)gm * K + k0 + ac;
#pragma unroll
            for (int i = 0; i < 4; ++i) s[i] = *(const short8*)(ap + 8 * i);
        } else {
#pragma unroll
            for (int i = 0; i < 4; ++i) s[i] = short8{0,0,0,0,0,0,0,0};
        }
        short* da = &As[ar * 72 + ac];
#pragma unroll
        for (int i = 0; i < 4; ++i) *(short8*)(da + i * 8) = s[i];
        const unsigned short* wp = Wt + (size_t)tid * K + k0;
        short* db = &Bs[tid * 72];
#pragma unroll
        for (int i = 0; i < 8; ++i) *(short8*)(db + i * 8) = *(const short8*)(wp + i * 8);
        __syncthreads();
#pragma unroll
        for (int ks = 0; ks < 2; ++ks) {
            short8 af[4], bf[8];
#pragma unroll
            for (int mi = 0; mi < 4; ++mi)
                af[mi] = *(short8*)&As[(wm + mi * 16 + lm) * 72 + ks * 32 + quad * 8];
#pragma unroll
            for (int ni = 0; ni < 8; ++ni)
                bf[ni] = *(short8*)&Bs[(wn + ni * 16 + lm) * 72 + ks * 32 + quad * 8];
#pragma unroll
            for (int mi = 0; mi < 4; ++mi)
#pragma unroll
                for (int ni = 0; ni < 8; ++ni)
                    acc[mi][ni] = __builtin_amdgcn_mfma_f32_16x16x32_bf16(
                        af[mi], bf[ni], acc[mi][ni], 0, 0, 0);
        }
        __syncthreads();
    }
    // ---- epilogue: residual + stats ----
    float g8[8], b8[8], bi8[8];
#pragma unroll
    for (int ni = 0; ni < 8; ++ni) {
        int gc = wn + ni * 16 + lm;
        g8[ni] = g[gc]; b8[ni] = beta[gc]; bi8[ni] = bias[gc];
    }
#pragma unroll
    for (int mi = 0; mi < 4; ++mi)
#pragma unroll
        for (int j = 0; j < 4; ++j) {
            int r  = wm + mi * 16 + quad * 4 + j;
            int gr = m0 + r;
            float s = 0.f, sq = 0.f;
            if (gr < M) {
#pragma unroll
                for (int ni = 0; ni < 8; ++ni) {
                    float v = acc[mi][ni][j] + bi8[ni] + out[(size_t)gr * 256 + wn + ni * 16 + lm];
                    acc[mi][ni][j] = v;
                    s += v; sq += v * v;
                }
            }
#pragma unroll
            for (int o = 1; o < 16; o <<= 1) {
                s  += __shfl_xor(s, o, 64);
                sq += __shfl_xor(sq, o, 64);
            }
            if (lm == 0) { red[r][(wn >> 7) * 2 + 0] = s; red[r][(wn >> 7) * 2 + 1] = sq; }
        }
    __syncthreads();
    if (tid < 128) {
        float S = red[tid][0] + red[tid][2];
        float Q = red[tid][1] + red[tid][3];
        float mean = S * (1.f / 256.f);
        float var  = Q * (1.f / 256.f) - mean * mean;
        mstat[tid][0] = mean;
        mstat[tid][1] = rsqrtf(var + 1e-5f);
    }
    __syncthreads();
#pragma unroll
    for (int mi = 0; mi < 4; ++mi)
#pragma unroll
        for (int j = 0; j < 4; ++j) {
            int r  = wm + mi * 16 + quad * 4 + j;
            int gr = m0 + r;
            if (gr >= M) continue;
            float mean = mstat[r][0], rs = mstat[r][1];
#pragma unroll
            for (int ni = 0; ni < 8; ++ni) {
                size_t idx = (size_t)gr * 256 + wn + ni * 16 + lm;
                float v = (acc[mi][ni][j] - mean) * rs * g8[ni] + b8[ni];
                out[idx]  = v;
                outb[idx] = f2bf(v);
                if (qb) qb[idx] = f2bf(v + pos[idx]);
            }
        }
}

// ---------------------------------------------------------------------------
// MSDA sampler v3: 2 queries/block.
// Phase 1: per (q,h,l,p) softmax + corner offsets/weights -> LDS (40B/pt).
// Phase 2: lanes = 4 corners x 4 channel-octets; one dwordx4 gather per step.
// ---------------------------------------------------------------------------
__global__ __launch_bounds__(256) void msda_sample_kernel(
    const unsigned short* __restrict__ value,  // bf16 (B,S,8,32)
    const unsigned short* __restrict__ oa,     // bf16 (B,S,384): 256 off | 128 logits
    const float* __restrict__ refpts,          // fp32 (B,S,4,2)
    unsigned short* __restrict__ accb)         // bf16 (B,S,256)
{
    __shared__ int pts[272 * 10];   // [P][4 corners x {off,w}] padded to 10 ints
    const int tid = threadIdx.x;
    const int q0  = blockIdx.x * 2;
    {
        const int qq = tid >> 7;
        const int q  = q0 + qq;
        const int jj = tid & 127;
        const int h  = jj >> 4, l = (jj >> 2) & 3, t = jj & 15;
        const int b  = q / S_N;
        const int Wi = 152 >> l;
        const int Hi = (100 >> l) + (l == 3);
        const float Wf = (float)Wi, Hf = (float)Hi;
        const int start = (l < 1) ? 0 : (l < 2) ? 15200 : (l < 3) ? 19000 : 19950;
        const unsigned short* oq = oa + (size_t)q * 384;
        unsigned op = *(const unsigned*)(oq + jj * 2);
        float ox = __builtin_bit_cast(float, op << 16);
        float oy = __builtin_bit_cast(float, op & 0xffff0000u);
        float2 rp = *(const float2*)(refpts + (size_t)q * 8 + l * 2);
        float logit = bf2f(oq[256 + jj]);
        float mx = logit;
#pragma unroll
        for (int o = 1; o < 16; o <<= 1) mx = fmaxf(mx, __shfl_xor(mx, o, 64));
        float e = expf(logit - mx);
        float sum = e;
#pragma unroll
        for (int o = 1; o < 16; o <<= 1) sum += __shfl_xor(sum, o, 64);
        float w = e / sum;
        float px = (rp.x + ox / Wf) * Wf - 0.5f;
        float py = (rp.y + oy / Hf) * Hf - 0.5f;
        float x0f = floorf(px), y0f = floorf(py);
        float fx = px - x0f, fy = py - y0f;
        int x0 = (int)x0f, y0 = (int)y0f;
        int base = b * S_N + start;
        int P = qq * 136 + h * 17 + t;
#pragma unroll
        for (int c = 0; c < 4; ++c) {
            int dx = c & 1, dy = c >> 1;
            int xi = x0 + dx, yi = y0 + dy;
            bool valid = (xi >= 0) & (xi < Wi) & (yi >= 0) & (yi < Hi);
            int xc = min(max(xi, 0), Wi - 1);
            int yc = min(max(yi, 0), Hi - 1);
            float cw = (dx ? fx : 1.f - fx) * (dy ? fy : 1.f - fy);
            int offby = ((base + yc * Wi + xc) * 256 + h * 32) * 2;
            pts[P * 10 + c * 2 + 0] = offby;
            pts[P * 10 + c * 2 + 1] = __builtin_bit_cast(int, valid ? w * cw : 0.f);
        }
    }
    __syncthreads();
    const int qq = tid >> 7;
    const int gl = tid & 127;
    const int hh = gl >> 4, lg = gl & 15;
    const int cn = lg & 3;                 // corner
    const int c8 = (lg >> 2) * 8;          // channel octet
    const char* vb = (const char*)value + c8 * 2;
    float a[8] = {};
    const int Pb = qq * 136 + hh * 17;
#pragma unroll
    for (int t = 0; t < 16; ++t) {
        int2 ow = *(const int2*)&pts[(Pb + t) * 10 + cn * 2];
        float w = __builtin_bit_cast(float, ow.y);
        short8 v8 = *(const short8*)(vb + ow.x);
#pragma unroll
        for (int i = 0; i < 8; ++i)
            a[i] = fmaf(w, bf2f((unsigned short)v8[i]), a[i]);
    }
#pragma unroll
    for (int o = 1; o < 4; o <<= 1)
#pragma unroll
        for (int i = 0; i < 8; ++i) a[i] += __shfl_xor(a[i], o, 64);
    if (cn == 0) {
        int4 pk;
        pk.x = (int)((unsigned)f2bf(a[0]) | ((unsigned)f2bf(a[1]) << 16));
        pk.y = (int)((unsigned)f2bf(a[2]) | ((unsigned)f2bf(a[3]) << 16));
        pk.z = (int)((unsigned)f2bf(a[4]) | ((unsigned)f2bf(a[5]) << 16));
        pk.w = (int)((unsigned)f2bf(a[6]) | ((unsigned)f2bf(a[7]) << 16));
        *(int4*)((char*)accb + ((size_t)(q0 + qq) * 256 + hh * 32 + c8) * 2) = pk;
    }
}

// ---------------------------------------------------------------------------
extern "C" void kernel_launch(void* const* d_in, const int* in_sizes, int n_in,
                              void* d_out, int out_size, void* d_ws, size_t ws_size,
                              hipStream_t stream)
{
    const float* src  = (const float*)d_in[0];
    const float* pos  = (const float*)d_in[1];
    const float* vr   = (const float*)d_in[2];
    const float* Wv   = (const float*)d_in[3];
    const float* bv   = (const float*)d_in[4];
    const float* Woff = (const float*)d_in[5];
    const float* boff = (const float*)d_in[6];
    const float* Wa   = (const float*)d_in[7];
    const float* ba   = (const float*)d_in[8];
    const float* Wo   = (const float*)d_in[9];
    const float* bo   = (const float*)d_in[10];
    const float* g1   = (const float*)d_in[11];
    const float* be1  = (const float*)d_in[12];
    const float* W1   = (const float*)d_in[13];
    const float* b1   = (const float*)d_in[14];
    const float* W2   = (const float*)d_in[15];
    const float* b2   = (const float*)d_in[16];
    const float* g2   = (const float*)d_in[17];
    const float* be2  = (const float*)d_in[18];

    float* out = (float*)d_out;
    float* ws  = (float*)d_ws;
    // Layout (floats), total ~155.1 MB:
    // [refpts][value bf16][oa bf16][slack][accb bf16][qb bf16][outb bf16][weights]
    // hidden bf16 (M x 1024) aliases value+oa+slack (all dead at FFN time).
    float* refpts = ws;
    float* valreg = refpts + 323200;
    float* oareg  = valreg + 5170432;
    float* slack  = oareg  + 7755648;
    float* accreg = slack  + 7755648;
    float* qreg   = accreg + 5170432;
    float* obreg  = qreg   + 5170432;
    unsigned short* value_bf = (unsigned short*)valreg;
    unsigned short* oa       = (unsigned short*)oareg;
    unsigned short* hidden   = (unsigned short*)valreg;
    unsigned short* accb     = (unsigned short*)accreg;
    unsigned short* qb       = (unsigned short*)qreg;
    unsigned short* outb     = (unsigned short*)obreg;
    unsigned short* wtv  = (unsigned short*)(obreg + 5170432);
    unsigned short* wtoa = wtv  + 6 * 65536;
    unsigned short* wto  = wtoa + 6 * 98304;
    unsigned short* wt1  = wto  + 6 * 65536;
    unsigned short* wt2  = wt1  + 6 * 262144;
    float* boa = (float*)(wt2 + 6 * 262144);   // 6*384 floats

    dim3 blk(256);
    compute_ref_kernel<<<(M_N + 255) / 256, 256, 0, stream>>>(vr, refpts);
    init_kernel<<<M_N, blk, 0, stream>>>(src, pos, out, outb, qb);
    transpose_w_kernel<<<dim3(8, 8, 6),  blk, 0, stream>>>(Wv,   wtv,  256, 256,  256, 0);
    transpose_w_kernel<<<dim3(8, 8, 6),  blk, 0, stream>>>(Woff, wtoa, 256, 256,  384, 0);
    transpose_w_kernel<<<dim3(4, 8, 6),  blk, 0, stream>>>(Wa,   wtoa, 256, 128,  384, 256);
    transpose_w_kernel<<<dim3(8, 8, 6),  blk, 0, stream>>>(Wo,   wto,  256, 256,  256, 0);
    transpose_w_kernel<<<dim3(32, 8, 6), blk, 0, stream>>>(W1,   wt1,  256, 1024, 1024, 0);
    transpose_w_kernel<<<dim3(8, 32, 6), blk, 0, stream>>>(W2,   wt2,  1024, 256, 256, 0);
    boa_kernel<<<6, 384, 0, stream>>>(boff, ba, boa);

    const int mt = (M_N + 127) / 128;   // 316
    for (int i = 0; i < 6; ++i) {
        // oa = (out+pos) @ [Woff|Wa] + [boff|ba]   (bf16 out)
        gemm_bf16<<<dim3(mt, 3), blk, 0, stream>>>(qb, wtoa + (size_t)i * 98304,
                                                   boa + i * 384, oa, M_N, 384, 256, 1);
        // value = out @ Wv + bv   (bf16 out)
        gemm_bf16<<<dim3(mt, 2), blk, 0, stream>>>(outb, wtv + (size_t)i * 65536,
                                                   bv + i * 256, value_bf, M_N, 256, 256, 1);
        // sampling
        msda_sample_kernel<<<M_N / 2, blk, 0, stream>>>(value_bf, oa, refpts, accb);
        // attn_out GEMM fused with residual+LN1
        gemm_bf16_ln<<<mt, blk, 0, stream>>>(accb, wto + (size_t)i * 65536, bo + i * 256,
                                             out, outb, g1 + i * 256, be1 + i * 256,
                                             nullptr, nullptr, M_N, 256);
        // hidden = relu(out @ W1 + b1)   (bf16, aliases value+oa+slack)
        gemm_bf16<<<dim3(mt, 8), blk, 0, stream>>>(outb, wt1 + (size_t)i * 262144,
                                                   b1 + i * 1024, hidden, M_N, 1024, 256, 2);
        // FFN2 GEMM fused with residual+LN2 (+ qb for next layer)
        gemm_bf16_ln<<<mt, blk, 0, stream>>>(hidden, wt2 + (size_t)i * 262144, b2 + i * 256,
                                             out, outb, g2 + i * 256, be2 + i * 256,
                                             pos, qb, M_N, 1024);
    }
}